// Round 6
// baseline (272.709 us; speedup 1.0000x reference)
//
#include <hip/hip_runtime.h>
#include <hip/hip_bf16.h>
#include <string.h>

typedef unsigned int uint_t;
typedef __attribute__((ext_vector_type(8))) short short8;
typedef __attribute__((ext_vector_type(4))) float floatx4;

__device__ __forceinline__ float4 fma4(float4 a, float s, float4 w){
  a.x += s*w.x; a.y += s*w.y; a.z += s*w.z; a.w += s*w.w; return a;
}
__device__ __forceinline__ float4 relu4(float4 a){
  return make_float4(fmaxf(a.x,0.f),fmaxf(a.y,0.f),fmaxf(a.z,0.f),fmaxf(a.w,0.f));
}
__device__ __forceinline__ float comp4(float4 v, int k){
  return k==0? v.x : k==1? v.y : k==2? v.z : v.w;
}
// RNE float->bf16 bits
__device__ __forceinline__ unsigned bf16rne(float f){
  unsigned u = __float_as_uint(f);
  return (u + 0x7fffu + ((u>>16)&1u)) >> 16;
}
// packed (hi<<16)|lo bf16 pair, hi+lo ~= f to ~2^-16 rel
__device__ __forceinline__ uint_t packbf(float f){
  unsigned hb = bf16rne(f);
  float hf = __uint_as_float(hb<<16);
  unsigned lb = bf16rne(f - hf);
  return (hb<<16) | lb;
}
__device__ __forceinline__ uint4 pack4(float4 v){
  uint4 u; u.x=packbf(v.x); u.y=packbf(v.y); u.z=packbf(v.z); u.w=packbf(v.w); return u;
}

// =============== K0: weight transpose+convert (bf16 hi/lo, [N][K] layout) ===============
__global__ __launch_bounds__(256) void convw_kernel(
    const float* __restrict__ wl1, const float* __restrict__ wr1,
    const float* __restrict__ wl2, const float* __restrict__ wr2,
    unsigned short* __restrict__ wl1Thi, unsigned short* __restrict__ wl1Tlo,
    unsigned short* __restrict__ wr1Thi, unsigned short* __restrict__ wr1Tlo,
    unsigned short* __restrict__ wl2Thi, unsigned short* __restrict__ wl2Tlo,
    unsigned short* __restrict__ wr2Thi, unsigned short* __restrict__ wr2Tlo)
{
  __shared__ float sm[32][33];
  const int bid = blockIdx.x, t = threadIdx.x;
  const float* in; unsigned short* ohi; unsigned short* olo; int K, tt;
  if (bid < 64)       { in=wl1; ohi=wl1Thi; olo=wl1Tlo; K=128; tt=bid; }
  else if (bid < 128) { in=wr1; ohi=wr1Thi; olo=wr1Tlo; K=128; tt=bid-64; }
  else if (bid < 384) { in=wl2; ohi=wl2Thi; olo=wl2Tlo; K=512; tt=bid-128; }
  else                { in=wr2; ohi=wr2Thi; olo=wr2Tlo; K=512; tt=bid-384; }
  const int N = 512;
  const int ktiles = K>>5;
  const int kt = tt % ktiles, nt = tt / ktiles;
  const int r = t>>5, c = t&31;
  #pragma unroll
  for (int i=0;i<4;i++)
    sm[r+i*8][c] = in[(size_t)(kt*32 + r + i*8)*N + nt*32 + c];
  __syncthreads();
  #pragma unroll
  for (int i=0;i<4;i++){
    const int n = nt*32 + r + i*8, k = kt*32 + c;
    const float f = sm[c][r+i*8];
    const unsigned hb = bf16rne(f);
    const float hf = __uint_as_float(hb<<16);
    const unsigned lb = bf16rne(f - hf);
    ohi[(size_t)n*K + k] = (unsigned short)hb;
    olo[(size_t)n*K + k] = (unsigned short)lb;
  }
}

// =============== K1: encoder + adjacency + x1 tap (x written packed bf16-pair) ===============
__global__ __launch_bounds__(256) void enc_kernel(
    const float* __restrict__ obs,
    const float* __restrict__ enc_w1, const float* __restrict__ enc_b1,
    const float* __restrict__ enc_w2, const float* __restrict__ enc_b2,
    uint_t* __restrict__ xpk,    // [4096][128] packed
    float* __restrict__ xcat,    // [128][1152]
    unsigned* __restrict__ adjw, int* __restrict__ aiw)
{
  __shared__ float s_pos[64];
  __shared__ float s_feats[512];
  __shared__ __align__(16) float s_h[32*132];
  __shared__ int s_ai;
  const int t = threadIdx.x, s = blockIdx.x;
  const float* ob = obs + s*577;

  if (t < 64) s_pos[t] = ob[(t>>1)*18 + (t&1)];
  for (int e=t; e<512; e+=256){ const int i=e>>4, f=e&15; s_feats[e] = ob[i*18+2+f]; }
  if (t==0){
    float a = ob[576];
    a = fminf(fmaxf(a, 0.f), 31.f);
    const int ai = (int)a;
    s_ai = ai; aiw[s] = ai;
  }
  __syncthreads();

  if (t < 32){
    const float px = s_pos[2*t], py = s_pos[2*t+1];
    const float R2 = 0.09f;
    unsigned m = 0u;
    for (int j=0;j<32;j++){
      const float dx = __fsub_rn(px, s_pos[2*j]), dy = __fsub_rn(py, s_pos[2*j+1]);
      const float d2 = __fadd_rn(__fmul_rn(dx,dx), __fmul_rn(dy,dy));
      if (d2 <= R2 || j==t) m |= (1u<<j);
    }
    adjw[s*32+t] = m;
  }

  // enc1
  {
    const int i = t>>3, c0 = (t&7)*16;
    float4 a0 = *(const float4*)(enc_b1+c0);
    float4 a1 = *(const float4*)(enc_b1+c0+4);
    float4 a2 = *(const float4*)(enc_b1+c0+8);
    float4 a3 = *(const float4*)(enc_b1+c0+12);
    for (int f=0; f<16; f++){
      const float xs = s_feats[i*16+f];
      const float* p = enc_w1 + f*128 + c0;
      a0 = fma4(a0, xs, *(const float4*)(p));
      a1 = fma4(a1, xs, *(const float4*)(p+4));
      a2 = fma4(a2, xs, *(const float4*)(p+8));
      a3 = fma4(a3, xs, *(const float4*)(p+12));
    }
    *(float4*)&s_h[i*132+c0]    = relu4(a0);
    *(float4*)&s_h[i*132+c0+4]  = relu4(a1);
    *(float4*)&s_h[i*132+c0+8]  = relu4(a2);
    *(float4*)&s_h[i*132+c0+12] = relu4(a3);
  }
  __syncthreads();

  // enc2 -> packed x + fp32 tap
  {
    const int i = t>>3, c0 = (t&7)*16;
    float4 a0 = *(const float4*)(enc_b2+c0);
    float4 a1 = *(const float4*)(enc_b2+c0+4);
    float4 a2 = *(const float4*)(enc_b2+c0+8);
    float4 a3 = *(const float4*)(enc_b2+c0+12);
    for (int k=0;k<128;k+=4){
      const float4 hv = *(const float4*)&s_h[i*132+k];
      #pragma unroll
      for (int kk=0;kk<4;kk++){
        const float* p = enc_w2 + (k+kk)*128 + c0;
        const float xs = comp4(hv,kk);
        a0 = fma4(a0, xs, *(const float4*)(p));
        a1 = fma4(a1, xs, *(const float4*)(p+4));
        a2 = fma4(a2, xs, *(const float4*)(p+8));
        a3 = fma4(a3, xs, *(const float4*)(p+12));
      }
    }
    a0 = relu4(a0); a1 = relu4(a1); a2 = relu4(a2); a3 = relu4(a3);
    uint_t* xp = xpk + ((size_t)s*32 + i)*128;
    *(uint4*)&xp[c0]    = pack4(a0);
    *(uint4*)&xp[c0+4]  = pack4(a1);
    *(uint4*)&xp[c0+8]  = pack4(a2);
    *(uint4*)&xp[c0+12] = pack4(a3);
    if (i == s_ai){
      float* xc = xcat + (size_t)s*1152;
      *(float4*)&xc[c0]    = a0;
      *(float4*)&xc[c0+4]  = a1;
      *(float4*)&xc[c0+8]  = a2;
      *(float4*)&xc[c0+12] = a3;
    }
  }
}

// =============== MFMA bf16x3 GEMM: C[M x 512-ish] = A @ B  (BT layout weights) ===============
// Block: 4 waves, tile 64 rows x 64 cols. ct0<ctsplit -> (B0,C0) else (B1,C1).
// A packed (hi<<16|lo) [row][KD]; B*Thi/lo [col][KD] bf16 bits.
template<int KD>
__global__ __launch_bounds__(256) void mfma_gemm(
    const uint_t* __restrict__ Apk,
    const unsigned short* __restrict__ B0hi, const unsigned short* __restrict__ B0lo,
    const unsigned short* __restrict__ B1hi, const unsigned short* __restrict__ B1lo,
    float* __restrict__ C0, float* __restrict__ C1,
    int nct, int ctsplit)
{
  const int t = threadIdx.x;
  const int w = t>>6, lane = t&63;
  const int bid = blockIdx.x;
  const int rt = bid / nct, ct0 = bid % nct;
  const unsigned short* Bhi; const unsigned short* Blo; float* C; int cb;
  if (ct0 < ctsplit){ Bhi = B0hi; Blo = B0lo; C = C0; cb = ct0*64; }
  else              { Bhi = B1hi; Blo = B1lo; C = C1; cb = (ct0-ctsplit)*64; }
  const int m = lane & 15, quad = lane >> 4;
  const int arow = rt*64 + w*16 + m;
  const uint_t* ap = Apk + (size_t)arow*KD + quad*8;
  floatx4 acc[4];
  #pragma unroll
  for (int i=0;i<4;i++) acc[i] = (floatx4){0.f,0.f,0.f,0.f};
  const unsigned short* bp0 = Bhi + (size_t)(cb +  0 + m)*KD + quad*8;
  const unsigned short* bp1 = Bhi + (size_t)(cb + 16 + m)*KD + quad*8;
  const unsigned short* bp2 = Bhi + (size_t)(cb + 32 + m)*KD + quad*8;
  const unsigned short* bp3 = Bhi + (size_t)(cb + 48 + m)*KD + quad*8;
  const size_t lod = (size_t)(Blo - Bhi);

  for (int k0=0; k0<KD; k0+=32){
    const uint4 ua0 = *(const uint4*)(ap);
    const uint4 ua1 = *(const uint4*)(ap+4);
    ap += 32;
    short8 ahi, alo;
    ahi[0]=(short)(ua0.x>>16); alo[0]=(short)(ua0.x);
    ahi[1]=(short)(ua0.y>>16); alo[1]=(short)(ua0.y);
    ahi[2]=(short)(ua0.z>>16); alo[2]=(short)(ua0.z);
    ahi[3]=(short)(ua0.w>>16); alo[3]=(short)(ua0.w);
    ahi[4]=(short)(ua1.x>>16); alo[4]=(short)(ua1.x);
    ahi[5]=(short)(ua1.y>>16); alo[5]=(short)(ua1.y);
    ahi[6]=(short)(ua1.z>>16); alo[6]=(short)(ua1.z);
    ahi[7]=(short)(ua1.w>>16); alo[7]=(short)(ua1.w);
    {
      const short8 bh = *(const short8*)(bp0);
      const short8 bl = *(const short8*)(bp0 + lod);
      acc[0] = __builtin_amdgcn_mfma_f32_16x16x32_bf16(ahi, bh, acc[0], 0,0,0);
      acc[0] = __builtin_amdgcn_mfma_f32_16x16x32_bf16(ahi, bl, acc[0], 0,0,0);
      acc[0] = __builtin_amdgcn_mfma_f32_16x16x32_bf16(alo, bh, acc[0], 0,0,0);
      bp0 += 32;
    }
    {
      const short8 bh = *(const short8*)(bp1);
      const short8 bl = *(const short8*)(bp1 + lod);
      acc[1] = __builtin_amdgcn_mfma_f32_16x16x32_bf16(ahi, bh, acc[1], 0,0,0);
      acc[1] = __builtin_amdgcn_mfma_f32_16x16x32_bf16(ahi, bl, acc[1], 0,0,0);
      acc[1] = __builtin_amdgcn_mfma_f32_16x16x32_bf16(alo, bh, acc[1], 0,0,0);
      bp1 += 32;
    }
    {
      const short8 bh = *(const short8*)(bp2);
      const short8 bl = *(const short8*)(bp2 + lod);
      acc[2] = __builtin_amdgcn_mfma_f32_16x16x32_bf16(ahi, bh, acc[2], 0,0,0);
      acc[2] = __builtin_amdgcn_mfma_f32_16x16x32_bf16(ahi, bl, acc[2], 0,0,0);
      acc[2] = __builtin_amdgcn_mfma_f32_16x16x32_bf16(alo, bh, acc[2], 0,0,0);
      bp2 += 32;
    }
    {
      const short8 bh = *(const short8*)(bp3);
      const short8 bl = *(const short8*)(bp3 + lod);
      acc[3] = __builtin_amdgcn_mfma_f32_16x16x32_bf16(ahi, bh, acc[3], 0,0,0);
      acc[3] = __builtin_amdgcn_mfma_f32_16x16x32_bf16(ahi, bl, acc[3], 0,0,0);
      acc[3] = __builtin_amdgcn_mfma_f32_16x16x32_bf16(alo, bh, acc[3], 0,0,0);
      bp3 += 32;
    }
  }
  const int crow0 = rt*64 + w*16 + quad*4;
  #pragma unroll
  for (int nt2=0; nt2<4; nt2++){
    const int col = cb + nt2*16 + m;
    #pragma unroll
    for (int r=0;r<4;r++)
      C[(size_t)(crow0 + r)*512 + col] = acc[nt2][r];
  }
}

// =============== K3: GAT layer-1 attention; x2 written packed in place of gr + tap ===============
__global__ __launch_bounds__(256) void attn1_kernel(
    const float* __restrict__ gl, const float* __restrict__ gr, // [4096][512]
    const float* __restrict__ att, const float* __restrict__ bias,
    const unsigned* __restrict__ adjw, const int* __restrict__ aiw,
    uint_t* __restrict__ x2pk,   // aliases gr buffer (packed in place, same indices)
    uint_t* __restrict__ a2tap,  // [128][512] packed
    float* __restrict__ xcat)    // [128][1152]
{
  __shared__ __align__(16) float s_gl[32*132];
  __shared__ __align__(16) float s_gr[32*132];
  __shared__ __align__(16) float s_att[128];
  __shared__ __align__(16) float s_b[128];
  __shared__ float s_lg[32*33];
  __shared__ unsigned s_adj[32];
  const int t = threadIdx.x;
  const int s = blockIdx.x >> 2, h = blockIdx.x & 3;
  const float* glp = gl + (size_t)s*32*512 + h*128;
  const float* grp = gr + (size_t)s*32*512 + h*128;

  {
    const int i = t>>3, c0 = (t&7)*16;
    #pragma unroll
    for (int q=0;q<4;q++){
      *(float4*)&s_gl[i*132 + c0 + q*4] = *(const float4*)&glp[(size_t)i*512 + c0 + q*4];
      *(float4*)&s_gr[i*132 + c0 + q*4] = *(const float4*)&grp[(size_t)i*512 + c0 + q*4];
    }
  }
  if (t < 128){ s_att[t] = att[h*128 + t]; s_b[t] = bias[h*128 + t]; }
  if (t >= 224) s_adj[t-224] = adjw[s*32 + (t-224)];
  const int ai = aiw[s];
  __syncthreads();

  // logits
  {
    const int i = t>>3, jb = t&7;
    float acc[4] = {0.f,0.f,0.f,0.f};
    for (int c=0;c<128;c+=4){
      const float4 g = *(const float4*)&s_gr[i*132+c];
      const float4 a = *(const float4*)&s_att[c];
      #pragma unroll
      for (int mm=0;mm<4;mm++){
        const float4 gj = *(const float4*)&s_gl[(jb+8*mm)*132 + c];
        float ex = g.x+gj.x; ex = fmaxf(ex, 0.2f*ex);
        float ey = g.y+gj.y; ey = fmaxf(ey, 0.2f*ey);
        float ez = g.z+gj.z; ez = fmaxf(ez, 0.2f*ez);
        float ew = g.w+gj.w; ew = fmaxf(ew, 0.2f*ew);
        acc[mm] += ex*a.x + ey*a.y + ez*a.z + ew*a.w;
      }
    }
    #pragma unroll
    for (int mm=0;mm<4;mm++) s_lg[i*33 + jb + 8*mm] = acc[mm];
  }
  __syncthreads();

  // masked softmax
  for (int rnd=0; rnd<4; rnd++){
    const int i = rnd*8 + (t>>5), j = t&31;
    const float lg = s_lg[i*33+j];
    const bool ok = (s_adj[i]>>j)&1u;
    float v = ok ? lg : -3.0e38f;
    #pragma unroll
    for (int d_=16; d_; d_>>=1) v = fmaxf(v, __shfl_xor(v, d_, 32));
    const float e = ok ? __expf(lg - v) : 0.f;
    float sum = e;
    #pragma unroll
    for (int d_=16; d_; d_>>=1) sum += __shfl_xor(sum, d_, 32);
    s_lg[i*33+j] = e / sum;
  }
  __syncthreads();

  // aggregate -> packed x2 (in place) + taps
  {
    const int i = t>>3, c0 = (t&7)*16;
    float4 o0 = make_float4(0.f,0.f,0.f,0.f), o1 = o0, o2 = o0, o3 = o0;
    for (int j=0;j<32;j++){
      const float al = s_lg[i*33+j];
      o0 = fma4(o0, al, *(const float4*)&s_gl[j*132 + c0]);
      o1 = fma4(o1, al, *(const float4*)&s_gl[j*132 + c0 + 4]);
      o2 = fma4(o2, al, *(const float4*)&s_gl[j*132 + c0 + 8]);
      o3 = fma4(o3, al, *(const float4*)&s_gl[j*132 + c0 + 12]);
    }
    const float4 b0 = *(const float4*)&s_b[c0];
    const float4 b1 = *(const float4*)&s_b[c0+4];
    const float4 b2 = *(const float4*)&s_b[c0+8];
    const float4 b3 = *(const float4*)&s_b[c0+12];
    o0 = relu4(make_float4(o0.x+b0.x, o0.y+b0.y, o0.z+b0.z, o0.w+b0.w));
    o1 = relu4(make_float4(o1.x+b1.x, o1.y+b1.y, o1.z+b1.z, o1.w+b1.w));
    o2 = relu4(make_float4(o2.x+b2.x, o2.y+b2.y, o2.z+b2.z, o2.w+b2.w));
    o3 = relu4(make_float4(o3.x+b3.x, o3.y+b3.y, o3.z+b3.z, o3.w+b3.w));
    const uint4 p0 = pack4(o0), p1 = pack4(o1), p2 = pack4(o2), p3 = pack4(o3);
    uint_t* xp = x2pk + ((size_t)s*32 + i)*512 + h*128;
    *(uint4*)&xp[c0]    = p0;
    *(uint4*)&xp[c0+4]  = p1;
    *(uint4*)&xp[c0+8]  = p2;
    *(uint4*)&xp[c0+12] = p3;
    if (i == ai){
      uint_t* tp = a2tap + (size_t)s*512 + h*128;
      *(uint4*)&tp[c0]    = p0;
      *(uint4*)&tp[c0+4]  = p1;
      *(uint4*)&tp[c0+8]  = p2;
      *(uint4*)&tp[c0+12] = p3;
      float* xc = xcat + (size_t)s*1152 + 128 + h*128;
      *(float4*)&xc[c0]    = o0;
      *(float4*)&xc[c0+4]  = o1;
      *(float4*)&xc[c0+8]  = o2;
      *(float4*)&xc[c0+12] = o3;
    }
  }
}

// =============== K6: attn2 (row ai) + x3 -> xcat[640..1152], one block per (s,h) ===============
__global__ __launch_bounds__(256) void attn2_kernel(
    const float* __restrict__ gl2, const float* __restrict__ grt,
    const float* __restrict__ att2, const float* __restrict__ bias2,
    const unsigned* __restrict__ adjw, const int* __restrict__ aiw,
    float* __restrict__ xcat)
{
  __shared__ __align__(16) float s_gl[32*132];
  __shared__ __align__(16) float s_gr[128];
  __shared__ __align__(16) float s_at[128];
  __shared__ __align__(16) float s_bb[128];
  __shared__ float s_lg[32];
  __shared__ float s_al[32];
  const int t = threadIdx.x;
  const int s = blockIdx.x >> 2, h = blockIdx.x & 3;
  const int ai = aiw[s];
  const unsigned arow = adjw[s*32+ai];
  {
    const int i = t>>3, c0 = (t&7)*16;
    const float* g0 = gl2 + ((size_t)(s*32+i))*512 + h*128;
    #pragma unroll
    for (int q=0;q<4;q++)
      *(float4*)&s_gl[i*132 + c0 + q*4] = *(const float4*)&g0[c0 + q*4];
  }
  if (t < 128) s_gr[t] = grt[(size_t)s*512 + h*128 + t];
  else { const int u=t-128; s_at[u] = att2[h*128+u]; s_bb[u] = bias2[h*128+u]; }
  __syncthreads();
  // logits for row ai
  {
    const int j = t>>3, p = t&7;
    float sum = 0.f;
    #pragma unroll
    for (int q=0;q<4;q++){
      const int c = p*16 + q*4;
      const float4 g = *(const float4*)&s_gl[j*132 + c];
      const float4 r = *(const float4*)&s_gr[c];
      const float4 a = *(const float4*)&s_at[c];
      float e0 = r.x+g.x; e0 = fmaxf(e0, 0.2f*e0);
      float e1 = r.y+g.y; e1 = fmaxf(e1, 0.2f*e1);
      float e2 = r.z+g.z; e2 = fmaxf(e2, 0.2f*e2);
      float e3 = r.w+g.w; e3 = fmaxf(e3, 0.2f*e3);
      sum += e0*a.x + e1*a.y + e2*a.z + e3*a.w;
    }
    sum += __shfl_xor(sum,1,64);
    sum += __shfl_xor(sum,2,64);
    sum += __shfl_xor(sum,4,64);
    if (p==0) s_lg[j] = sum;
  }
  __syncthreads();
  if (t < 32){
    const float lg = s_lg[t];
    const bool ok = (arow>>t)&1u;
    float v = ok ? lg : -3.0e38f;
    #pragma unroll
    for (int d_=16; d_; d_>>=1) v = fmaxf(v, __shfl_xor(v, d_, 32));
    const float e = ok ? __expf(lg - v) : 0.f;
    float sm = e;
    #pragma unroll
    for (int d_=16; d_; d_>>=1) sm += __shfl_xor(sm, d_, 32);
    s_al[t] = e / sm;
  }
  __syncthreads();
  if (t < 128){
    float acc = 0.f;
    #pragma unroll 8
    for (int j=0;j<32;j++) acc += s_al[j] * s_gl[j*132 + t];
    xcat[(size_t)s*1152 + 640 + h*128 + t] = fmaxf(acc + s_bb[t], 0.f);
  }
}

// =============== K7: dueling heads layer1+partial layer2, block per (s, q/v) ===============
__global__ __launch_bounds__(256) void heads_kernel(
    const float* __restrict__ xcatg,
    const float* __restrict__ q_w1, const float* __restrict__ q_b1,
    const float* __restrict__ q_w2, const float* __restrict__ q_b2,
    const float* __restrict__ v_w1, const float* __restrict__ v_b1,
    const float* __restrict__ v_w2, const float* __restrict__ v_b2,
    float* __restrict__ qpart, float* __restrict__ vpart)
{
  __shared__ __align__(16) float s_x[1152];
  __shared__ float s_p[4*6];
  const int t = threadIdx.x;
  const int s = blockIdx.x >> 1, isv = blockIdx.x & 1;
  for (int e=t; e<288; e+=256)
    *(float4*)&s_x[e*4] = *(const float4*)&xcatg[(size_t)s*1152 + e*4];
  __syncthreads();
  const float* W  = isv ? v_w1 : q_w1;
  const float* B1 = isv ? v_b1 : q_b1;
  float acc = 0.f;
  #pragma unroll 16
  for (int k=0;k<1152;k++) acc += s_x[k] * W[(size_t)k*256 + t];
  const float hv = fmaxf(acc + B1[t], 0.f);
  const int w = t>>6, lane = t&63;
  if (!isv){
    float p[5];
    #pragma unroll
    for (int o=0;o<5;o++) p[o] = hv * q_w2[t*5+o];
    #pragma unroll
    for (int d_=32; d_; d_>>=1){
      #pragma unroll
      for (int o=0;o<5;o++) p[o] += __shfl_xor(p[o], d_, 64);
    }
    if (lane==0){
      #pragma unroll
      for (int o=0;o<5;o++) s_p[w*6+o] = p[o];
    }
  } else {
    float p = hv * v_w2[t];
    #pragma unroll
    for (int d_=32; d_; d_>>=1) p += __shfl_xor(p, d_, 64);
    if (lane==0) s_p[w*6] = p;
  }
  __syncthreads();
  if (!isv){
    if (t < 5) qpart[s*8+t] = s_p[t] + s_p[6+t] + s_p[12+t] + s_p[18+t] + q_b2[t];
  } else {
    if (t == 0) vpart[s] = s_p[0] + s_p[6] + s_p[12] + s_p[18] + v_b2[0];
  }
}

// =============== K8: final combine ===============
__global__ void final_kernel(const float* __restrict__ qpart, const float* __restrict__ vpart,
                             float* __restrict__ out, int bs)
{
  const int s = threadIdx.x;
  if (s < bs){
    const float q0 = qpart[s*8+0], q1 = qpart[s*8+1], q2 = qpart[s*8+2],
                q3 = qpart[s*8+3], q4 = qpart[s*8+4];
    const float mean = (q0+q1+q2+q3+q4) / 5.0f;
    const float v = vpart[s];
    out[s*5+0] = q0 - mean + v;
    out[s*5+1] = q1 - mean + v;
    out[s*5+2] = q2 - mean + v;
    out[s*5+3] = q3 - mean + v;
    out[s*5+4] = q4 - mean + v;
  }
}

extern "C" void kernel_launch(void* const* d_in, const int* in_sizes, int n_in,
                              void* d_out, int out_size, void* d_ws, size_t ws_size,
                              hipStream_t stream) {
  (void)n_in; (void)out_size; (void)ws_size;
  const float* obs    = (const float*)d_in[0];
  const float* enc_w1 = (const float*)d_in[1];
  const float* enc_b1 = (const float*)d_in[2];
  const float* enc_w2 = (const float*)d_in[3];
  const float* enc_b2 = (const float*)d_in[4];
  const float* wl1    = (const float*)d_in[5];
  const float* wr1    = (const float*)d_in[6];
  const float* att1   = (const float*)d_in[7];
  const float* bias1  = (const float*)d_in[8];
  const float* wl2    = (const float*)d_in[9];
  const float* wr2    = (const float*)d_in[10];
  const float* att2   = (const float*)d_in[11];
  const float* bias2  = (const float*)d_in[12];
  const float* q_w1   = (const float*)d_in[13];
  const float* q_b1   = (const float*)d_in[14];
  const float* q_w2   = (const float*)d_in[15];
  const float* q_b2   = (const float*)d_in[16];
  const float* v_w1   = (const float*)d_in[17];
  const float* v_b1   = (const float*)d_in[18];
  const float* v_w2   = (const float*)d_in[19];
  const float* v_b2   = (const float*)d_in[20];

  // workspace layout (bytes)
  char* ws = (char*)d_ws;
  uint_t*   x_pk   = (uint_t*)  (ws + 0);           // 4096*128*4   = 2,097,152
  float*    xcat   = (float*)   (ws + 2097152);     // 128*1152*4   =   589,824
  unsigned* adjw   = (unsigned*)(ws + 2686976);     // 16,384
  int*      aiw    = (int*)     (ws + 2703360);     // 512
  float*    gl_buf = (float*)   (ws + 2703872);     // 8,388,608
  float*    gr_buf = (float*)   (ws + 11092480);    // 8,388,608 (x2 packed in place later)
  unsigned short* wl1Thi = (unsigned short*)(ws + 19481088);  // 131,072 each
  unsigned short* wl1Tlo = (unsigned short*)(ws + 19612160);
  unsigned short* wr1Thi = (unsigned short*)(ws + 19743232);
  unsigned short* wr1Tlo = (unsigned short*)(ws + 19874304);
  unsigned short* wl2Thi = (unsigned short*)(ws + 20005376);  // 524,288 each
  unsigned short* wl2Tlo = (unsigned short*)(ws + 20529664);
  unsigned short* wr2Thi = (unsigned short*)(ws + 21053952);
  unsigned short* wr2Tlo = (unsigned short*)(ws + 21578240);
  uint_t*   a2tap  = (uint_t*)  (ws + 22102528);    // 262,144
  float*    grt    = (float*)   (ws + 22364672);    // 262,144
  float*    qpart  = (float*)   (ws + 22626816);    // 4,096
  float*    vpart  = (float*)   (ws + 22630912);    // 512
  // total ~22.6 MB

  const int bs = in_sizes[0] / 577;   // 128

  convw_kernel<<<640, 256, 0, stream>>>(wl1, wr1, wl2, wr2,
                                        wl1Thi, wl1Tlo, wr1Thi, wr1Tlo,
                                        wl2Thi, wl2Tlo, wr2Thi, wr2Tlo);

  enc_kernel<<<bs, 256, 0, stream>>>(obs, enc_w1, enc_b1, enc_w2, enc_b2,
                                     x_pk, xcat, adjw, aiw);

  // proj1: gl1|gr1 = x @ [wl1|wr1]  (M=4096, K=128, N=512+512)
  mfma_gemm<128><<<(bs/2)*16, 256, 0, stream>>>(x_pk, wl1Thi, wl1Tlo, wr1Thi, wr1Tlo,
                                                gl_buf, gr_buf, 16, 8);

  attn1_kernel<<<bs*4, 256, 0, stream>>>(gl_buf, gr_buf, att1, bias1, adjw, aiw,
                                         (uint_t*)gr_buf, a2tap, xcat);

  // proj2: gl2 = x2 @ wl2  (M=4096, K=512, N=512)
  mfma_gemm<512><<<(bs/2)*8, 256, 0, stream>>>((const uint_t*)gr_buf,
                                               wl2Thi, wl2Tlo, wl2Thi, wl2Tlo,
                                               gl_buf, gl_buf, 8, 8);

  // gr2 tap rows: grt = x2tap @ wr2  (M=128, K=512, N=512)
  mfma_gemm<512><<<(bs/64)*8, 256, 0, stream>>>(a2tap,
                                                wr2Thi, wr2Tlo, wr2Thi, wr2Tlo,
                                                grt, grt, 8, 8);

  attn2_kernel<<<bs*4, 256, 0, stream>>>(gl_buf, grt, att2, bias2, adjw, aiw, xcat);

  heads_kernel<<<bs*2, 256, 0, stream>>>(xcat, q_w1, q_b1, q_w2, q_b2,
                                         v_w1, v_b1, v_w2, v_b2, qpart, vpart);

  final_kernel<<<1, 128, 0, stream>>>(qpart, vpart, (float*)d_out, bs);
}